// Round 1
// baseline (411.948 us; speedup 1.0000x reference)
//
#include <hip/hip_runtime.h>
#include <stdint.h>
#include <math.h>

#define EMB 2048
#define NHq 16
#define NGk 4
#define HD 128
#define Bb 2
#define Tt 2048
#define MROWS (Bb*Tt)      // 4096
#define QKVN 3072          // 2048 q + 512 k + 512 v

typedef __bf16 bf16x8 __attribute__((ext_vector_type(8)));
typedef float f32x4 __attribute__((ext_vector_type(4)));
typedef unsigned short u16;

__device__ __forceinline__ u16 f2bf(float f) {
    unsigned int u = __float_as_uint(f);
    u += 0x7fff + ((u >> 16) & 1);          // round-to-nearest-even
    return (u16)(u >> 16);
}

#define GLOAD_LDS16(g, l) \
    __builtin_amdgcn_global_load_lds((const __attribute__((address_space(1))) void*)(g), \
                                     (__attribute__((address_space(3))) void*)(l), 16, 0, 0)

// ---------------- cast f32 -> bf16, vectorized ----------------
__global__ void cast_bf16_kernel(const float* __restrict__ src, u16* __restrict__ dst, int n4) {
    int i = blockIdx.x * blockDim.x + threadIdx.x;
    if (i < n4) {
        float4 v = reinterpret_cast<const float4*>(src)[i];
        ushort4 o;
        o.x = f2bf(v.x); o.y = f2bf(v.y); o.z = f2bf(v.z); o.w = f2bf(v.w);
        reinterpret_cast<ushort4*>(dst)[i] = o;
    }
}

// ---------------- RoPE cos/sin tables: [T][64] ----------------
__global__ void rope_tables_kernel(float* __restrict__ ctab, float* __restrict__ stab) {
    int t = blockIdx.x, i = threadIdx.x;     // grid T, block 64
    float inv = powf(10000.f, -2.f * (float)i / (float)HD);
    float ang = (float)t * inv;
    ctab[t * 64 + i] = cosf(ang);
    stab[t * 64 + i] = sinf(ang);
}

// ---------------- RoPE + relayout: lin[M][3072] f32 -> out[B][nh][T][HD] bf16 ----------------
__global__ void rope_kernel(const float* __restrict__ lin, const float* __restrict__ ctab,
                            const float* __restrict__ stab, u16* __restrict__ out,
                            int coloff, int nh, float scale) {
    // grid (T/4, nh, B), block (64,4)
    int i = threadIdx.x;                       // pair index 0..63
    int tt = blockIdx.x * 4 + threadIdx.y;
    int h = blockIdx.y, b = blockIdx.z;
    const float2 xv = *reinterpret_cast<const float2*>(
        &lin[((size_t)(b * Tt + tt)) * QKVN + coloff + h * HD + 2 * i]);
    float c = ctab[tt * 64 + i], s = stab[tt * 64 + i];
    ushort2 o;
    o.x = f2bf((xv.x * c - xv.y * s) * scale);
    o.y = f2bf((xv.x * s + xv.y * c) * scale);
    *reinterpret_cast<ushort2*>(&out[(((size_t)(b * nh + h)) * Tt + tt) * HD + 2 * i]) = o;
}

// ---------------- V relayout+transpose: lin -> Vt[B][NG][HD][T] bf16 ----------------
__global__ void vtrans_kernel(const float* __restrict__ lin, u16* __restrict__ vt) {
    // grid (T/64, NG, B), block (64,8)
    int tx = threadIdx.x, dy = threadIdx.y;
    int tt = blockIdx.x * 64 + tx;
    int g = blockIdx.y, b = blockIdx.z;
    const float* src = &lin[((size_t)(b * Tt + tt)) * QKVN + EMB + NGk * HD + g * HD];
    u16* dst = &vt[(((size_t)(b * NGk + g)) * HD) * Tt + tt];
    #pragma unroll
    for (int k = 0; k < 16; ++k) {
        int d = dy + k * 8;
        dst[(size_t)d * Tt] = f2bf(src[d]);
    }
}

// ---------------- bf16 GEMM: C[M][N] f32 = A[M][K]bf16 @ W[N][K]bf16 ^T ----------------
__global__ __launch_bounds__(256) void gemm_bt(const u16* __restrict__ A, const u16* __restrict__ W,
                                               float* __restrict__ C, int M, int N, int K) {
    __shared__ u16 Atile[128 * 32];
    __shared__ u16 Btile[128 * 32];
    const int brow = blockIdx.x * 128;
    const int bcol = blockIdx.y * 128;
    const int t = threadIdx.x;
    const int w = t >> 6, l = t & 63;
    const int lr = l & 15, lq = l >> 4;
    const int wr = (w >> 1) * 64, wc = (w & 1) * 64;
    f32x4 acc[4][4] = {};
    const int nkt = K >> 5;
    for (int kt = 0; kt < nkt; ++kt) {
        const int k0 = kt * 32;
        #pragma unroll
        for (int i = 0; i < 2; ++i) {
            int f = i * 256 + t;
            int row = f >> 2, cb = (f & 3) * 8;
            GLOAD_LDS16(A + (size_t)(brow + row) * K + k0 + cb, &Atile[(i * 256 + w * 64) * 8]);
            GLOAD_LDS16(W + (size_t)(bcol + row) * K + k0 + cb, &Btile[(i * 256 + w * 64) * 8]);
        }
        __syncthreads();
        bf16x8 a[4], b[4];
        #pragma unroll
        for (int m = 0; m < 4; ++m)
            a[m] = *reinterpret_cast<const bf16x8*>(&Atile[(wr + m * 16 + lr) * 32 + lq * 8]);
        #pragma unroll
        for (int n = 0; n < 4; ++n)
            b[n] = *reinterpret_cast<const bf16x8*>(&Btile[(wc + n * 16 + lr) * 32 + lq * 8]);
        #pragma unroll
        for (int m = 0; m < 4; ++m)
            #pragma unroll
            for (int n = 0; n < 4; ++n)
                acc[m][n] = __builtin_amdgcn_mfma_f32_16x16x32_bf16(a[m], b[n], acc[m][n], 0, 0, 0);
        __syncthreads();
    }
    #pragma unroll
    for (int m = 0; m < 4; ++m)
        #pragma unroll
        for (int n = 0; n < 4; ++n)
            #pragma unroll
            for (int r = 0; r < 4; ++r)
                C[(size_t)(brow + wr + m * 16 + lq * 4 + r) * N + bcol + wc + n * 16 + lr] = acc[m][n][r];
}

// ---------------- flash attention ----------------
// Q [B][NH][T][HD] bf16 (pre-scaled by rsqrt(HD)*log2e), K [B][NG][T][HD] bf16,
// Vt [B][NG][HD][T] bf16, Out [B][T][EMB] bf16.  1 block = 64 q rows of one head.
__global__ __launch_bounds__(256) void flash_attn(const u16* __restrict__ Q, const u16* __restrict__ K,
                                                  const u16* __restrict__ Vt, u16* __restrict__ Out) {
    __shared__ u16 Klds[32 * 128];
    __shared__ u16 Vlds[128 * 32];
    __shared__ u16 Plds[4][16 * 32];
    const int qb = blockIdx.x;      // 32 q-blocks
    const int h = blockIdx.y;       // 16 heads
    const int b = blockIdx.z;       // 2
    const int g = h >> 2;           // kv group
    const int t = threadIdx.x;
    const int w = t >> 6, l = t & 63;
    const int lr = l & 15, lq = l >> 4;

    // Q fragments for this wave's 16 rows (held in registers all kernel)
    const size_t qbase = (((size_t)(b * NHq + h)) * Tt + qb * 64 + w * 16) * HD;
    bf16x8 qf[4];
    #pragma unroll
    for (int d = 0; d < 4; ++d)
        qf[d] = *reinterpret_cast<const bf16x8*>(&Q[qbase + (size_t)lr * HD + d * 32 + lq * 8]);

    f32x4 o[8] = {};
    float mrow[4], lrow[4];
    #pragma unroll
    for (int r = 0; r < 4; ++r) { mrow[r] = -1e20f; lrow[r] = 0.f; }

    const int qrow0 = qb * 64 + w * 16 + lq * 4;
    const size_t kbase  = ((size_t)(b * NGk + g)) * Tt * HD;
    const size_t vtbase = ((size_t)(b * NGk + g)) * HD * Tt;
    const int nkt = 2 * qb + 2;

    for (int kt = 0; kt < nkt; ++kt) {
        const int kp0 = kt * 32;
        // ---- stage K tile [32][128] (XOR-swizzled) and Vt tile [128][32] (XOR-swizzled) ----
        #pragma unroll
        for (int i = 0; i < 2; ++i) {
            int f = i * 256 + t;
            {   // K: 512 chunks of 16B; row = f>>4 (0..31), colblk = f&15
                int row = f >> 4, cb = f & 15;
                uint4 kv = *reinterpret_cast<const uint4*>(&K[kbase + (size_t)(kp0 + row) * HD + cb * 8]);
                int bo = (row * 256 + cb * 16) ^ ((row & 7) << 4);
                *reinterpret_cast<uint4*>((char*)Klds + bo) = kv;
            }
            {   // Vt: 512 chunks; d = f>>2 (0..127), seg = f&3
                int d = f >> 2, seg = f & 3;
                uint4 vv = *reinterpret_cast<const uint4*>(&Vt[vtbase + (size_t)d * Tt + kp0 + seg * 8]);
                int bo = (d * 64 + seg * 16) ^ ((d & 3) << 4);
                *reinterpret_cast<uint4*>((char*)Vlds + bo) = vv;
            }
        }
        __syncthreads();

        // ---- S = Q K^T (two 16x16 tiles over the 32 kv rows) ----
        f32x4 s0 = {}, s1 = {};
        #pragma unroll
        for (int d = 0; d < 4; ++d) {
            int bo0 = (lr * 256 + d * 64 + lq * 16) ^ ((lr & 7) << 4);
            int bo1 = ((16 + lr) * 256 + d * 64 + lq * 16) ^ (((16 + lr) & 7) << 4);
            bf16x8 k0 = *reinterpret_cast<const bf16x8*>((const char*)Klds + bo0);
            bf16x8 k1 = *reinterpret_cast<const bf16x8*>((const char*)Klds + bo1);
            s0 = __builtin_amdgcn_mfma_f32_16x16x32_bf16(qf[d], k0, s0, 0, 0, 0);
            s1 = __builtin_amdgcn_mfma_f32_16x16x32_bf16(qf[d], k1, s1, 0, 0, 0);
        }

        // ---- causal mask + online softmax (rows = lq*4+r, cols = lr across 16 lanes) ----
        float p0[4], p1[4], mx[4];
        #pragma unroll
        for (int r = 0; r < 4; ++r) {
            int qp = qrow0 + r;
            p0[r] = (kp0 + lr      <= qp) ? s0[r] : -1e30f;
            p1[r] = (kp0 + 16 + lr <= qp) ? s1[r] : -1e30f;
            mx[r] = fmaxf(p0[r], p1[r]);
        }
        #pragma unroll
        for (int off = 1; off < 16; off <<= 1)
            #pragma unroll
            for (int r = 0; r < 4; ++r)
                mx[r] = fmaxf(mx[r], __shfl_xor(mx[r], off));
        float alpha[4];
        #pragma unroll
        for (int r = 0; r < 4; ++r) {
            float mn = fmaxf(fmaxf(mrow[r], mx[r]), -1e20f);
            alpha[r] = exp2f(mrow[r] - mn);
            p0[r] = exp2f(p0[r] - mn);      // masked -> exp2(-1e30+1e20) = 0
            p1[r] = exp2f(p1[r] - mn);
            mrow[r] = mn;
        }
        float rs[4];
        #pragma unroll
        for (int r = 0; r < 4; ++r) rs[r] = p0[r] + p1[r];
        #pragma unroll
        for (int off = 1; off < 16; off <<= 1)
            #pragma unroll
            for (int r = 0; r < 4; ++r) rs[r] += __shfl_xor(rs[r], off);
        #pragma unroll
        for (int r = 0; r < 4; ++r) lrow[r] = lrow[r] * alpha[r] + rs[r];

        // ---- P -> per-wave LDS (bf16), re-read in A-fragment layout ----
        #pragma unroll
        for (int r = 0; r < 4; ++r) {
            int row = lq * 4 + r;
            Plds[w][row * 32 + lr]      = f2bf(p0[r]);
            Plds[w][row * 32 + lr + 16] = f2bf(p1[r]);
        }
        #pragma unroll
        for (int n = 0; n < 8; ++n)
            #pragma unroll
            for (int r = 0; r < 4; ++r)
                o[n][r] *= alpha[r];
        bf16x8 pf = *reinterpret_cast<const bf16x8*>(&Plds[w][lr * 32 + lq * 8]);

        // ---- O += P V ----
        #pragma unroll
        for (int n = 0; n < 8; ++n) {
            int dcol = n * 16 + lr;
            int bo = (dcol * 64 + lq * 16) ^ ((dcol & 3) << 4);
            bf16x8 vf = *reinterpret_cast<const bf16x8*>((const char*)Vlds + bo);
            o[n] = __builtin_amdgcn_mfma_f32_16x16x32_bf16(pf, vf, o[n], 0, 0, 0);
        }
        __syncthreads();
    }

    // ---- epilogue: O / l, write [B][T][EMB] bf16 ----
    #pragma unroll
    for (int r = 0; r < 4; ++r) lrow[r] = 1.f / lrow[r];
    const size_t obase = ((size_t)b * Tt) * EMB + (size_t)h * HD;
    #pragma unroll
    for (int n = 0; n < 8; ++n)
        #pragma unroll
        for (int r = 0; r < 4; ++r) {
            int trow = qb * 64 + w * 16 + lq * 4 + r;
            Out[obase + (size_t)trow * EMB + n * 16 + lr] = f2bf(o[n][r] * lrow[r]);
        }
}

// ---------------- launcher ----------------
extern "C" void kernel_launch(void* const* d_in, const int* in_sizes, int n_in,
                              void* d_out, int out_size, void* d_ws, size_t ws_size,
                              hipStream_t stream) {
    (void)in_sizes; (void)n_in; (void)out_size; (void)ws_size;
    const float* x  = (const float*)d_in[0];
    const float* Wq = (const float*)d_in[1];
    const float* Wk = (const float*)d_in[2];
    const float* Wv = (const float*)d_in[3];
    const float* Wo = (const float*)d_in[4];
    float* out = (float*)d_out;

    char* ws = (char*)d_ws;
    size_t off = 0;
    auto alloc = [&](size_t bytes) { char* p = ws + off; off += (bytes + 255) & ~(size_t)255; return p; };

    u16* w_bf    = (u16*)alloc((size_t)(QKVN * EMB + EMB * EMB) * 2);  // Wq|Wk|Wv then Wo
    u16* x_bf    = (u16*)alloc((size_t)MROWS * EMB * 2);
    float* qkv_lin = (float*)alloc((size_t)MROWS * QKVN * 4);
    u16* Qb      = (u16*)alloc((size_t)Bb * NHq * Tt * HD * 2);
    u16* Kb      = (u16*)alloc((size_t)Bb * NGk * Tt * HD * 2);
    u16* Vtb     = (u16*)alloc((size_t)Bb * NGk * HD * Tt * 2);
    float* ctab  = (float*)alloc((size_t)Tt * 64 * 4);
    float* stab  = (float*)alloc((size_t)Tt * 64 * 4);
    u16* attnout = (u16*)qkv_lin;   // alias: qkv_lin dead after rope/vtrans

    u16* wq_bf = w_bf;
    u16* wk_bf = w_bf + (size_t)EMB * EMB;
    u16* wv_bf = wk_bf + (size_t)NGk * HD * EMB;
    u16* wo_bf = wv_bf + (size_t)NGk * HD * EMB;

    // 1. casts
    cast_bf16_kernel<<<(MROWS * EMB / 4 + 255) / 256, 256, 0, stream>>>(x, x_bf, MROWS * EMB / 4);
    cast_bf16_kernel<<<(EMB * EMB / 4 + 255) / 256, 256, 0, stream>>>(Wq, wq_bf, EMB * EMB / 4);
    cast_bf16_kernel<<<(NGk * HD * EMB / 4 + 255) / 256, 256, 0, stream>>>(Wk, wk_bf, NGk * HD * EMB / 4);
    cast_bf16_kernel<<<(NGk * HD * EMB / 4 + 255) / 256, 256, 0, stream>>>(Wv, wv_bf, NGk * HD * EMB / 4);
    cast_bf16_kernel<<<(EMB * EMB / 4 + 255) / 256, 256, 0, stream>>>(Wo, wo_bf, EMB * EMB / 4);
    rope_tables_kernel<<<Tt, 64, 0, stream>>>(ctab, stab);

    // 2. fused QKV projection: qkv_lin[4096][3072] = x_bf @ [Wq;Wk;Wv]^T
    gemm_bt<<<dim3(MROWS / 128, QKVN / 128), 256, 0, stream>>>(x_bf, w_bf, qkv_lin, MROWS, QKVN, EMB);

    // 3. RoPE + relayout (+ fold softmax scale*log2e into Q)
    const float qscale = 1.44269504088896f / sqrtf((float)HD);
    rope_kernel<<<dim3(Tt / 4, NHq, Bb), dim3(64, 4), 0, stream>>>(qkv_lin, ctab, stab, Qb, 0, NHq, qscale);
    rope_kernel<<<dim3(Tt / 4, NGk, Bb), dim3(64, 4), 0, stream>>>(qkv_lin, ctab, stab, Kb, EMB, NGk, 1.0f);
    vtrans_kernel<<<dim3(Tt / 64, NGk, Bb), dim3(64, 8), 0, stream>>>(qkv_lin, Vtb);

    // 4. flash attention -> attnout bf16 [B][T][EMB]  (aliases qkv_lin, inputs already consumed)
    flash_attn<<<dim3(Tt / 64, NHq, Bb), 256, 0, stream>>>(Qb, Kb, Vtb, attnout);

    // 5. output projection: out = attnout @ Wo^T  (f32 out)
    gemm_bt<<<dim3(MROWS / 128, EMB / 128), 256, 0, stream>>>(attnout, wo_bf, out, MROWS, EMB, EMB);
}

// Round 2
// 354.694 us; speedup vs baseline: 1.1614x; 1.1614x over previous
//
#include <hip/hip_runtime.h>
#include <stdint.h>
#include <math.h>

#define EMB 2048
#define NHq 16
#define NGk 4
#define HD 128
#define Bb 2
#define Tt 2048
#define MROWS (Bb*Tt)      // 4096
#define QKVN 3072          // 2048 q + 512 k + 512 v
#define NQT 32             // q-tiles of 64 rows per (b,h)

typedef __bf16 bf16x8 __attribute__((ext_vector_type(8)));
typedef float f32x4 __attribute__((ext_vector_type(4)));
typedef unsigned short u16;

__device__ __forceinline__ u16 f2bf(float f) {
    unsigned int u = __float_as_uint(f);
    u += 0x7fff + ((u >> 16) & 1);          // round-to-nearest-even
    return (u16)(u >> 16);
}

#define GLOAD_LDS16(g, l) \
    __builtin_amdgcn_global_load_lds((const __attribute__((address_space(1))) void*)(g), \
                                     (__attribute__((address_space(3))) void*)(l), 16, 0, 0)

// ---------------- cast f32 -> bf16, vectorized ----------------
__global__ void cast_bf16_kernel(const float* __restrict__ src, u16* __restrict__ dst, int n4) {
    int i = blockIdx.x * blockDim.x + threadIdx.x;
    if (i < n4) {
        float4 v = reinterpret_cast<const float4*>(src)[i];
        ushort4 o;
        o.x = f2bf(v.x); o.y = f2bf(v.y); o.z = f2bf(v.z); o.w = f2bf(v.w);
        reinterpret_cast<ushort4*>(dst)[i] = o;
    }
}

// ---------------- RoPE cos/sin tables: [T][64] ----------------
__global__ void rope_tables_kernel(float* __restrict__ ctab, float* __restrict__ stab) {
    int t = blockIdx.x, i = threadIdx.x;     // grid T, block 64
    float inv = powf(10000.f, -2.f * (float)i / (float)HD);
    float ang = (float)t * inv;
    ctab[t * 64 + i] = cosf(ang);
    stab[t * 64 + i] = sinf(ang);
}

// ---------------- RoPE + relayout: lin[M][3072] f32 -> out[B][nh][T][HD] bf16 ----------------
__global__ void rope_kernel(const float* __restrict__ lin, const float* __restrict__ ctab,
                            const float* __restrict__ stab, u16* __restrict__ out,
                            int coloff, int nh, float scale) {
    // grid (T/4, nh, B), block (64,4)
    int i = threadIdx.x;                       // pair index 0..63
    int tt = blockIdx.x * 4 + threadIdx.y;
    int h = blockIdx.y, b = blockIdx.z;
    const float2 xv = *reinterpret_cast<const float2*>(
        &lin[((size_t)(b * Tt + tt)) * QKVN + coloff + h * HD + 2 * i]);
    float c = ctab[tt * 64 + i], s = stab[tt * 64 + i];
    ushort2 o;
    o.x = f2bf((xv.x * c - xv.y * s) * scale);
    o.y = f2bf((xv.x * s + xv.y * c) * scale);
    *reinterpret_cast<ushort2*>(&out[(((size_t)(b * nh + h)) * Tt + tt) * HD + 2 * i]) = o;
}

// ---------------- V relayout+transpose: lin -> Vt[B][NG][HD][T] bf16 ----------------
__global__ void vtrans_kernel(const float* __restrict__ lin, u16* __restrict__ vt) {
    // grid (T/64, NG, B), block (64,8)
    int tx = threadIdx.x, dy = threadIdx.y;
    int tt = blockIdx.x * 64 + tx;
    int g = blockIdx.y, b = blockIdx.z;
    const float* src = &lin[((size_t)(b * Tt + tt)) * QKVN + EMB + NGk * HD + g * HD];
    u16* dst = &vt[(((size_t)(b * NGk + g)) * HD) * Tt + tt];
    #pragma unroll
    for (int k = 0; k < 16; ++k) {
        int d = dy + k * 8;
        dst[(size_t)d * Tt] = f2bf(src[d]);
    }
}

// ---------------- bf16 GEMM: C[M][N] f32 = A[M][K]bf16 @ W[N][K]bf16 ^T ----------------
__global__ __launch_bounds__(256) void gemm_bt(const u16* __restrict__ A, const u16* __restrict__ W,
                                               float* __restrict__ C, int M, int N, int K) {
    __shared__ u16 Atile[128 * 32];
    __shared__ u16 Btile[128 * 32];
    const int brow = blockIdx.x * 128;
    const int bcol = blockIdx.y * 128;
    const int t = threadIdx.x;
    const int w = t >> 6, l = t & 63;
    const int lr = l & 15, lq = l >> 4;
    const int wr = (w >> 1) * 64, wc = (w & 1) * 64;
    f32x4 acc[4][4] = {};
    const int nkt = K >> 5;
    for (int kt = 0; kt < nkt; ++kt) {
        const int k0 = kt * 32;
        #pragma unroll
        for (int i = 0; i < 2; ++i) {
            int f = i * 256 + t;
            int row = f >> 2, cb = (f & 3) * 8;
            GLOAD_LDS16(A + (size_t)(brow + row) * K + k0 + cb, &Atile[(i * 256 + w * 64) * 8]);
            GLOAD_LDS16(W + (size_t)(bcol + row) * K + k0 + cb, &Btile[(i * 256 + w * 64) * 8]);
        }
        __syncthreads();
        bf16x8 a[4], b[4];
        #pragma unroll
        for (int m = 0; m < 4; ++m)
            a[m] = *reinterpret_cast<const bf16x8*>(&Atile[(wr + m * 16 + lr) * 32 + lq * 8]);
        #pragma unroll
        for (int n = 0; n < 4; ++n)
            b[n] = *reinterpret_cast<const bf16x8*>(&Btile[(wc + n * 16 + lr) * 32 + lq * 8]);
        #pragma unroll
        for (int m = 0; m < 4; ++m)
            #pragma unroll
            for (int n = 0; n < 4; ++n)
                acc[m][n] = __builtin_amdgcn_mfma_f32_16x16x32_bf16(a[m], b[n], acc[m][n], 0, 0, 0);
        __syncthreads();
    }
    #pragma unroll
    for (int m = 0; m < 4; ++m)
        #pragma unroll
        for (int n = 0; n < 4; ++n)
            #pragma unroll
            for (int r = 0; r < 4; ++r)
                C[(size_t)(brow + wr + m * 16 + lq * 4 + r) * N + bcol + wc + n * 16 + lr] = acc[m][n][r];
}

// ---------------- flash attention v2: diagonal-paired, KVBLK=64 ----------------
// Q [B][NH][T][HD] bf16 (pre-scaled by rsqrt(HD)*log2e), K [B][NG][T][HD] bf16,
// Vt [B][NG][HD][T] bf16, Out [B][T][EMB] bf16.
// Block = q-tiles {i, 31-i} of one head (128 q rows) -> constant 33 compute-steps/block.
__global__ __launch_bounds__(256, 2) void flash_attn(const u16* __restrict__ Q, const u16* __restrict__ K,
                                                     const u16* __restrict__ Vt, u16* __restrict__ Out) {
    __shared__ u16 Klds[64 * 128];        // [kv 64][d 128], row-swizzled
    __shared__ u16 Vlds[128 * 64];        // [d 128][kv 64], row-swizzled
    __shared__ u16 Plds[4][16 * 64];      // per-wave [qrow 16][kv 64], row-swizzled
    const int ilo = blockIdx.x;           // 0..15
    const int ihi = NQT - 1 - ilo;        // 16..31
    const int h = blockIdx.y;
    const int b = blockIdx.z;
    const int g = h >> 2;
    const int t = threadIdx.x;
    const int w = t >> 6, l = t & 63;
    const int lr = l & 15, lq = l >> 4;

    // Q fragments: 16 rows of lo tile + 16 rows of hi tile per wave
    const size_t qhead = ((size_t)(b * NHq + h)) * Tt;
    const size_t qblo = (qhead + ilo * 64 + w * 16) * HD;
    const size_t qbhi = (qhead + ihi * 64 + w * 16) * HD;
    bf16x8 qfl[4], qfh[4];
    #pragma unroll
    for (int d = 0; d < 4; ++d) {
        qfl[d] = *reinterpret_cast<const bf16x8*>(&Q[qblo + (size_t)lr * HD + d * 32 + lq * 8]);
        qfh[d] = *reinterpret_cast<const bf16x8*>(&Q[qbhi + (size_t)lr * HD + d * 32 + lq * 8]);
    }

    f32x4 ol[8] = {}, oh[8] = {};
    float ml[4], ll[4], mh[4], lh[4];
    #pragma unroll
    for (int r = 0; r < 4; ++r) { ml[r] = -1e20f; ll[r] = 0.f; mh[r] = -1e20f; lh[r] = 0.f; }

    const int qlo0 = ilo * 64 + w * 16 + lq * 4;
    const int qhi0 = ihi * 64 + w * 16 + lq * 4;
    const size_t kbase  = ((size_t)(b * NGk + g)) * Tt * HD;
    const size_t vtbase = ((size_t)(b * NGk + g)) * HD * Tt;
    const int nkt = NQT - ilo;            // 17..32 staged tiles; compute = 33 q-tile-steps

    // staging regs (T14 issue-early / write-late)
    uint4 kreg[4], vreg[4];
    // K chunk c = j*256+t: row=c>>4 (0..63), cb=c&15 ; V chunk: d=c>>3 (0..127), seg=c&7
    const int krow = t >> 4, kcb = t & 15;          // +j*16 rows
    const int vd = t >> 3, vseg = t & 7;            // +j*32 rows
    {   // prologue: issue tile 0
        #pragma unroll
        for (int j = 0; j < 4; ++j) {
            kreg[j] = *reinterpret_cast<const uint4*>(&K[kbase + (size_t)(krow + j * 16) * HD + kcb * 8]);
            vreg[j] = *reinterpret_cast<const uint4*>(&Vt[vtbase + (size_t)(vd + j * 32) * Tt + vseg * 8]);
        }
    }

    for (int kt = 0; kt < nkt; ++kt) {
        const int kp0 = kt * 64;
        // ---- write staged regs -> LDS (swizzled) ----
        #pragma unroll
        for (int j = 0; j < 4; ++j) {
            int row = krow + j * 16;
            int bo = row * 256 + ((kcb * 16) ^ ((row & 7) << 4));
            *reinterpret_cast<uint4*>((char*)Klds + bo) = kreg[j];
            int d = vd + j * 32;
            int bv = d * 128 + ((vseg * 16) ^ ((d & 7) << 4));
            *reinterpret_cast<uint4*>((char*)Vlds + bv) = vreg[j];
        }
        __syncthreads();
        // ---- issue loads for next tile (fly under compute) ----
        if (kt + 1 < nkt) {
            const int kp1 = kp0 + 64;
            #pragma unroll
            for (int j = 0; j < 4; ++j) {
                kreg[j] = *reinterpret_cast<const uint4*>(&K[kbase + (size_t)(kp1 + krow + j * 16) * HD + kcb * 8]);
                vreg[j] = *reinterpret_cast<const uint4*>(&Vt[vtbase + (size_t)(vd + j * 32) * Tt + kp1 + vseg * 8]);
            }
        }

        const bool lo_act = (kt <= ilo);
        // ---- S = Q K^T : 4 col-tiles of 16, K-frags shared between lo/hi ----
        f32x4 sl[4] = {}, sh[4] = {};
        #pragma unroll
        for (int ct = 0; ct < 4; ++ct) {
            #pragma unroll
            for (int d = 0; d < 4; ++d) {
                int row = ct * 16 + lr;
                int bo = row * 256 + ((d * 64 + lq * 16) ^ ((row & 7) << 4));
                bf16x8 kf = *reinterpret_cast<const bf16x8*>((const char*)Klds + bo);
                if (lo_act) sl[ct] = __builtin_amdgcn_mfma_f32_16x16x32_bf16(qfl[d], kf, sl[ct], 0, 0, 0);
                sh[ct] = __builtin_amdgcn_mfma_f32_16x16x32_bf16(qfh[d], kf, sh[ct], 0, 0, 0);
            }
        }

        // ---- online softmax (rows lane-spread: row = lq*4+r, col = ct*16+lr) ----
        float all4[4], alh4[4];
        // --- hi half (always active) ---
        {
            const bool diag = (kt == nkt - 1);
            float p[4][4], mx[4];
            #pragma unroll
            for (int r = 0; r < 4; ++r) mx[r] = -1e30f;
            #pragma unroll
            for (int ct = 0; ct < 4; ++ct)
                #pragma unroll
                for (int r = 0; r < 4; ++r) {
                    float v = sh[ct][r];
                    if (diag && (kp0 + ct * 16 + lr > qhi0 + r)) v = -1e30f;
                    p[ct][r] = v;
                    mx[r] = fmaxf(mx[r], v);
                }
            #pragma unroll
            for (int off = 1; off < 16; off <<= 1)
                #pragma unroll
                for (int r = 0; r < 4; ++r) mx[r] = fmaxf(mx[r], __shfl_xor(mx[r], off));
            float rs[4];
            #pragma unroll
            for (int r = 0; r < 4; ++r) {
                float mn = fmaxf(mh[r], mx[r]);
                alh4[r] = exp2f(mh[r] - mn);
                mh[r] = mn;
                float s = 0.f;
                #pragma unroll
                for (int ct = 0; ct < 4; ++ct) { p[ct][r] = exp2f(p[ct][r] - mn); s += p[ct][r]; }
                rs[r] = s;
            }
            #pragma unroll
            for (int off = 1; off < 16; off <<= 1)
                #pragma unroll
                for (int r = 0; r < 4; ++r) rs[r] += __shfl_xor(rs[r], off);
            #pragma unroll
            for (int r = 0; r < 4; ++r) lh[r] = lh[r] * alh4[r] + rs[r];
            #pragma unroll
            for (int ct = 0; ct < 4; ++ct)
                #pragma unroll
                for (int r = 0; r < 4; ++r) {
                    int row = lq * 4 + r;
                    int bo = row * 128 + (((ct * 16 + lr) * 2) ^ ((row & 7) << 4));
                    *reinterpret_cast<u16*>((char*)Plds[w] + bo) = f2bf(p[ct][r]);
                }
        }
        bf16x8 pfh0, pfh1;
        {
            int bo0 = lr * 128 + ((lq * 16) ^ ((lr & 7) << 4));
            int bo1 = lr * 128 + ((64 + lq * 16) ^ ((lr & 7) << 4));
            pfh0 = *reinterpret_cast<const bf16x8*>((const char*)Plds[w] + bo0);
            pfh1 = *reinterpret_cast<const bf16x8*>((const char*)Plds[w] + bo1);
        }
        // --- lo half ---
        bf16x8 pfl0, pfl1;
        if (lo_act) {
            const bool diag = (kt == ilo);
            float p[4][4], mx[4];
            #pragma unroll
            for (int r = 0; r < 4; ++r) mx[r] = -1e30f;
            #pragma unroll
            for (int ct = 0; ct < 4; ++ct)
                #pragma unroll
                for (int r = 0; r < 4; ++r) {
                    float v = sl[ct][r];
                    if (diag && (kp0 + ct * 16 + lr > qlo0 + r)) v = -1e30f;
                    p[ct][r] = v;
                    mx[r] = fmaxf(mx[r], v);
                }
            #pragma unroll
            for (int off = 1; off < 16; off <<= 1)
                #pragma unroll
                for (int r = 0; r < 4; ++r) mx[r] = fmaxf(mx[r], __shfl_xor(mx[r], off));
            float rs[4];
            #pragma unroll
            for (int r = 0; r < 4; ++r) {
                float mn = fmaxf(ml[r], mx[r]);
                all4[r] = exp2f(ml[r] - mn);
                ml[r] = mn;
                float s = 0.f;
                #pragma unroll
                for (int ct = 0; ct < 4; ++ct) { p[ct][r] = exp2f(p[ct][r] - mn); s += p[ct][r]; }
                rs[r] = s;
            }
            #pragma unroll
            for (int off = 1; off < 16; off <<= 1)
                #pragma unroll
                for (int r = 0; r < 4; ++r) rs[r] += __shfl_xor(rs[r], off);
            #pragma unroll
            for (int r = 0; r < 4; ++r) ll[r] = ll[r] * all4[r] + rs[r];
            #pragma unroll
            for (int ct = 0; ct < 4; ++ct)
                #pragma unroll
                for (int r = 0; r < 4; ++r) {
                    int row = lq * 4 + r;
                    int bo = row * 128 + (((ct * 16 + lr) * 2) ^ ((row & 7) << 4));
                    *reinterpret_cast<u16*>((char*)Plds[w] + bo) = f2bf(p[ct][r]);
                }
            int bo0 = lr * 128 + ((lq * 16) ^ ((lr & 7) << 4));
            int bo1 = lr * 128 + ((64 + lq * 16) ^ ((lr & 7) << 4));
            pfl0 = *reinterpret_cast<const bf16x8*>((const char*)Plds[w] + bo0);
            pfl1 = *reinterpret_cast<const bf16x8*>((const char*)Plds[w] + bo1);
        }

        // ---- rescale O, then O += P V (V-frags shared lo/hi) ----
        #pragma unroll
        for (int n = 0; n < 8; ++n)
            #pragma unroll
            for (int r = 0; r < 4; ++r) {
                oh[n][r] *= alh4[r];
                if (lo_act) ol[n][r] *= all4[r];
            }
        #pragma unroll
        for (int n = 0; n < 8; ++n) {
            int dcol = n * 16 + lr;
            int bv0 = dcol * 128 + ((lq * 16) ^ ((dcol & 7) << 4));
            int bv1 = dcol * 128 + ((64 + lq * 16) ^ ((dcol & 7) << 4));
            bf16x8 vf0 = *reinterpret_cast<const bf16x8*>((const char*)Vlds + bv0);
            bf16x8 vf1 = *reinterpret_cast<const bf16x8*>((const char*)Vlds + bv1);
            oh[n] = __builtin_amdgcn_mfma_f32_16x16x32_bf16(pfh0, vf0, oh[n], 0, 0, 0);
            oh[n] = __builtin_amdgcn_mfma_f32_16x16x32_bf16(pfh1, vf1, oh[n], 0, 0, 0);
            if (lo_act) {
                ol[n] = __builtin_amdgcn_mfma_f32_16x16x32_bf16(pfl0, vf0, ol[n], 0, 0, 0);
                ol[n] = __builtin_amdgcn_mfma_f32_16x16x32_bf16(pfl1, vf1, ol[n], 0, 0, 0);
            }
        }
        __syncthreads();
    }

    // ---- epilogue: O / l, write [B][T][EMB] bf16 for both tiles ----
    #pragma unroll
    for (int r = 0; r < 4; ++r) { ll[r] = 1.f / ll[r]; lh[r] = 1.f / lh[r]; }
    const size_t obase = ((size_t)b * Tt) * EMB + (size_t)h * HD;
    #pragma unroll
    for (int n = 0; n < 8; ++n)
        #pragma unroll
        for (int r = 0; r < 4; ++r) {
            int rl = ilo * 64 + w * 16 + lq * 4 + r;
            int rh = ihi * 64 + w * 16 + lq * 4 + r;
            Out[obase + (size_t)rl * EMB + n * 16 + lr] = f2bf(ol[n][r] * ll[r]);
            Out[obase + (size_t)rh * EMB + n * 16 + lr] = f2bf(oh[n][r] * lh[r]);
        }
}

// ---------------- launcher ----------------
extern "C" void kernel_launch(void* const* d_in, const int* in_sizes, int n_in,
                              void* d_out, int out_size, void* d_ws, size_t ws_size,
                              hipStream_t stream) {
    (void)in_sizes; (void)n_in; (void)out_size; (void)ws_size;
    const float* x  = (const float*)d_in[0];
    const float* Wq = (const float*)d_in[1];
    const float* Wk = (const float*)d_in[2];
    const float* Wv = (const float*)d_in[3];
    const float* Wo = (const float*)d_in[4];
    float* out = (float*)d_out;

    char* ws = (char*)d_ws;
    size_t off = 0;
    auto alloc = [&](size_t bytes) { char* p = ws + off; off += (bytes + 255) & ~(size_t)255; return p; };

    u16* w_bf    = (u16*)alloc((size_t)(QKVN * EMB + EMB * EMB) * 2);  // Wq|Wk|Wv then Wo
    u16* x_bf    = (u16*)alloc((size_t)MROWS * EMB * 2);
    float* qkv_lin = (float*)alloc((size_t)MROWS * QKVN * 4);
    u16* Qb      = (u16*)alloc((size_t)Bb * NHq * Tt * HD * 2);
    u16* Kb      = (u16*)alloc((size_t)Bb * NGk * Tt * HD * 2);
    u16* Vtb     = (u16*)alloc((size_t)Bb * NGk * HD * Tt * 2);
    float* ctab  = (float*)alloc((size_t)Tt * 64 * 4);
    float* stab  = (float*)alloc((size_t)Tt * 64 * 4);
    u16* attnout = (u16*)qkv_lin;   // alias: qkv_lin dead after rope/vtrans

    u16* wq_bf = w_bf;
    u16* wk_bf = w_bf + (size_t)EMB * EMB;
    u16* wv_bf = wk_bf + (size_t)NGk * HD * EMB;
    u16* wo_bf = wv_bf + (size_t)NGk * HD * EMB;

    // 1. casts
    cast_bf16_kernel<<<(MROWS * EMB / 4 + 255) / 256, 256, 0, stream>>>(x, x_bf, MROWS * EMB / 4);
    cast_bf16_kernel<<<(EMB * EMB / 4 + 255) / 256, 256, 0, stream>>>(Wq, wq_bf, EMB * EMB / 4);
    cast_bf16_kernel<<<(NGk * HD * EMB / 4 + 255) / 256, 256, 0, stream>>>(Wk, wk_bf, NGk * HD * EMB / 4);
    cast_bf16_kernel<<<(NGk * HD * EMB / 4 + 255) / 256, 256, 0, stream>>>(Wv, wv_bf, NGk * HD * EMB / 4);
    cast_bf16_kernel<<<(EMB * EMB / 4 + 255) / 256, 256, 0, stream>>>(Wo, wo_bf, EMB * EMB / 4);
    rope_tables_kernel<<<Tt, 64, 0, stream>>>(ctab, stab);

    // 2. fused QKV projection: qkv_lin[4096][3072] = x_bf @ [Wq;Wk;Wv]^T
    gemm_bt<<<dim3(MROWS / 128, QKVN / 128), 256, 0, stream>>>(x_bf, w_bf, qkv_lin, MROWS, QKVN, EMB);

    // 3. RoPE + relayout (+ fold softmax scale*log2e into Q)
    const float qscale = 1.44269504088896f / sqrtf((float)HD);
    rope_kernel<<<dim3(Tt / 4, NHq, Bb), dim3(64, 4), 0, stream>>>(qkv_lin, ctab, stab, Qb, 0, NHq, qscale);
    rope_kernel<<<dim3(Tt / 4, NGk, Bb), dim3(64, 4), 0, stream>>>(qkv_lin, ctab, stab, Kb, EMB, NGk, 1.0f);
    vtrans_kernel<<<dim3(Tt / 64, NGk, Bb), dim3(64, 8), 0, stream>>>(qkv_lin, Vtb);

    // 4. flash attention (diagonal-paired) -> attnout bf16 [B][T][EMB]
    flash_attn<<<dim3(NQT / 2, NHq, Bb), 256, 0, stream>>>(Qb, Kb, Vtb, attnout);

    // 5. output projection: out = attnout @ Wo^T  (f32 out)
    gemm_bt<<<dim3(MROWS / 128, EMB / 128), 256, 0, stream>>>(attnout, wo_bf, out, MROWS, EMB, EMB);
}